// Round 1
// 426.831 us; speedup vs baseline: 1.0352x; 1.0352x over previous
//
#include <hip/hip_runtime.h>
#include <hip/hip_bf16.h>

#define N_POINTS 1000000
#define FEAT 64
#define BSEG 128
#define EPS 1e-5f
#define CHUNK 1024
#define NBLK_SEG ((N_POINTS + CHUNK - 1) / CHUNK)   // 977

// ---- biased ordered-uint encoding for float atomic max ----
// enc(x) = ordered(x) - ordered(-inf)  =>  enc(-inf) = 0, so init is memset(0).
#define ENC_BIAS 0x007FFFFFu   // ordered(-inf)

__device__ __forceinline__ unsigned ordered_enc(float f) {
    unsigned u = __float_as_uint(f);
    unsigned o = (u & 0x80000000u) ? ~u : (u | 0x80000000u);
    return o - ENC_BIAS;
}
__device__ __forceinline__ float ordered_dec(unsigned v) {
    unsigned o = v + ENC_BIAS;
    unsigned u = (o & 0x80000000u) ? (o & 0x7fffffffu) : ~o;
    return __uint_as_float(u);
}

__device__ __forceinline__ void fmax4(float4& m, const float4 v) {
    m.x = fmaxf(m.x, v.x); m.y = fmaxf(m.y, v.y);
    m.z = fmaxf(m.z, v.z); m.w = fmaxf(m.w, v.w);
}

// ---- segment max over sorted batch ids ----
// Thread = (point-lane r 0..31) x (32B feature octet q 0..7).
// FAST PATH (single-segment chunk, ~87% of blocks): branch-free 4-stream
// load+fmax loop (8 outstanding dwordx4 loads/thread), shuffle-reduce over
// the 32 r-lanes, 8 LDS atomics per representative lane, 64 global atomics
// per block. SLOW PATH (boundary chunk): original per-point id logic.
__global__ __launch_bounds__(256) void k_segmax(const float4* __restrict__ feat,
                                                const int* __restrict__ batch,
                                                unsigned* __restrict__ pool) {
    __shared__ unsigned short sb[CHUNK];
    __shared__ unsigned spool[4 * FEAT];
    const int t = threadIdx.x;
    const int base = blockIdx.x * CHUNK;
    int rem = N_POINTS - base;
    if (rem > CHUNK) rem = CHUNK;

    const int q = t & 7;
    const int r = t >> 3;
    const float4 NEG = make_float4(-INFINITY, -INFINITY, -INFINITY, -INFINITY);

    const int segFirst = batch[base];
    const int segLast  = batch[base + rem - 1];

    if (segFirst == segLast) {
        // ---------- fast path: whole chunk belongs to one segment ----------
        if (t < FEAT) spool[t] = 0u;
        __syncthreads();

        float4 mA0 = NEG, mA1 = NEG, mB0 = NEG, mB1 = NEG;
        float4 mC0 = NEG, mC1 = NEG, mD0 = NEG, mD1 = NEG;

        const float4* p = feat + (size_t)(base + r) * 16 + q * 2;
        if (rem == CHUNK) {
            // 4 streams at i = r, r+32, r+64, r+96; stride 128 points; 8 iters
            #pragma unroll 2
            for (int it = 0; it < 8; ++it) {
                const float4* pp = p + (size_t)it * 2048;   // 128 points * 16
                float4 a0 = pp[0],    a1 = pp[1];
                float4 b0 = pp[512],  b1 = pp[513];
                float4 c0 = pp[1024], c1 = pp[1025];
                float4 d0 = pp[1536], d1 = pp[1537];
                fmax4(mA0, a0); fmax4(mA1, a1);
                fmax4(mB0, b0); fmax4(mB1, b1);
                fmax4(mC0, c0); fmax4(mC1, c1);
                fmax4(mD0, d0); fmax4(mD1, d1);
            }
        } else {
            // partial last chunk (single block): guarded single-stream loop
            for (int i = r; i < rem; i += 32, p += 512) {
                float4 a0 = p[0], a1 = p[1];
                fmax4(mA0, a0); fmax4(mA1, a1);
            }
        }

        // combine streams -> one pair (8 floats = feature octet q)
        fmax4(mA0, mB0); fmax4(mC0, mD0); fmax4(mA0, mC0);
        fmax4(mA1, mB1); fmax4(mC1, mD1); fmax4(mA1, mC1);

        // reduce across the 8 r-values within each wave (lanes xor 8,16,32)
        #pragma unroll
        for (int mask = 8; mask <= 32; mask <<= 1) {
            mA0.x = fmaxf(mA0.x, __shfl_xor(mA0.x, mask, 64));
            mA0.y = fmaxf(mA0.y, __shfl_xor(mA0.y, mask, 64));
            mA0.z = fmaxf(mA0.z, __shfl_xor(mA0.z, mask, 64));
            mA0.w = fmaxf(mA0.w, __shfl_xor(mA0.w, mask, 64));
            mA1.x = fmaxf(mA1.x, __shfl_xor(mA1.x, mask, 64));
            mA1.y = fmaxf(mA1.y, __shfl_xor(mA1.y, mask, 64));
            mA1.z = fmaxf(mA1.z, __shfl_xor(mA1.z, mask, 64));
            mA1.w = fmaxf(mA1.w, __shfl_xor(mA1.w, mask, 64));
        }

        // one representative lane per (wave, q): 4 waves contend per address
        if ((t & 63) < 8) {
            unsigned e[8] = { ordered_enc(mA0.x), ordered_enc(mA0.y),
                              ordered_enc(mA0.z), ordered_enc(mA0.w),
                              ordered_enc(mA1.x), ordered_enc(mA1.y),
                              ordered_enc(mA1.z), ordered_enc(mA1.w) };
            unsigned* sp = &spool[q * 8];
            #pragma unroll
            for (int j = 0; j < 8; ++j) atomicMax(&sp[j], e[j]);
        }
        __syncthreads();

        if (t < FEAT) {
            unsigned v = spool[t];
            if (v != 0u) atomicMax(&pool[segFirst * FEAT + t], v);
        }
        return;
    }

    // ---------- slow path: chunk contains a segment boundary ----------
    for (int i = t; i < CHUNK; i += 256)
        sb[i] = (i < rem) ? (unsigned short)batch[base + i] : (unsigned short)0xFFFF;
    spool[t] = 0u;   // 256 entries == 4*FEAT; 0 == enc(-inf)
    __syncthreads();

    const int seg0 = sb[0];

    auto flush = [&](int seg, float4 a, float4 b) {
        unsigned e[8] = { ordered_enc(a.x), ordered_enc(a.y), ordered_enc(a.z), ordered_enc(a.w),
                          ordered_enc(b.x), ordered_enc(b.y), ordered_enc(b.z), ordered_enc(b.w) };
        int slot = seg - seg0;
        if (slot >= 0 && slot < 4) {
            unsigned* p = &spool[slot * FEAT + q * 8];
            #pragma unroll
            for (int j = 0; j < 8; ++j) atomicMax(&p[j], e[j]);
        } else {
            unsigned* p = &pool[seg * FEAT + q * 8];
            #pragma unroll
            for (int j = 0; j < 8; ++j) atomicMax(&p[j], e[j]);
        }
    };

    float4 mA0 = NEG, mA1 = NEG, mB0 = NEG, mB1 = NEG;
    int curA = -1, curB = -1;

    int iA = r, iB = r + 32;
    for (; iB < rem; iA += 64, iB += 64) {
        const float4* pA = &feat[(size_t)(base + iA) * 16 + q * 2];
        const float4* pB = &feat[(size_t)(base + iB) * 16 + q * 2];
        float4 a0 = pA[0], a1 = pA[1];
        float4 b0 = pB[0], b1 = pB[1];
        int sA = sb[iA], sB = sb[iB];

        if (sA != curA) {
            if (curA >= 0) flush(curA, mA0, mA1);
            curA = sA; mA0 = NEG; mA1 = NEG;
        }
        fmax4(mA0, a0); fmax4(mA1, a1);

        if (sB != curB) {
            if (curB >= 0) flush(curB, mB0, mB1);
            curB = sB; mB0 = NEG; mB1 = NEG;
        }
        fmax4(mB0, b0); fmax4(mB1, b1);
    }
    if (iA < rem) {   // tail point for stream A (last partial chunk only)
        const float4* pA = &feat[(size_t)(base + iA) * 16 + q * 2];
        float4 a0 = pA[0], a1 = pA[1];
        int sA = sb[iA];
        if (sA != curA) {
            if (curA >= 0) flush(curA, mA0, mA1);
            curA = sA; mA0 = NEG; mA1 = NEG;
        }
        fmax4(mA0, a0); fmax4(mA1, a1);
    }
    if (curA >= 0) flush(curA, mA0, mA1);
    if (curB >= 0) flush(curB, mB0, mB1);
    __syncthreads();

    unsigned v = spool[t];
    if (v != 0u) {
        int slot = t >> 6;
        atomicMax(&pool[(seg0 + slot) * FEAT + (t & 63)], v);
    }
}

// ---- fused LayerNorm + proj + fc1 + fc2 : one block per row, 1024 threads ----
__global__ __launch_bounds__(1024) void k_mlp(const unsigned* __restrict__ pool,
                                              const float* __restrict__ ln_g,
                                              const float* __restrict__ ln_b,
                                              const float* __restrict__ pw,
                                              const float* __restrict__ pb,
                                              const float* __restrict__ w1,
                                              const float* __restrict__ b1,
                                              const float* __restrict__ w2,
                                              const float* __restrict__ b2,
                                              float* __restrict__ h2out) {
    __shared__ float xn[64];
    __shared__ float lat[512];
    __shared__ float h1s[256];
    __shared__ float red[1024];
    const int b = blockIdx.x, t = threadIdx.x;

    if (t < 64) {
        float x = ordered_dec(pool[b * 64 + t]);
        float s = x;
        #pragma unroll
        for (int off = 32; off > 0; off >>= 1) s += __shfl_xor(s, off, 64);
        float mu = s * (1.0f / 64.0f);
        float d = x - mu;
        float s2 = d * d;
        #pragma unroll
        for (int off = 32; off > 0; off >>= 1) s2 += __shfl_xor(s2, off, 64);
        float var = s2 * (1.0f / 64.0f);
        xn[t] = d * rsqrtf(var + EPS) * ln_g[t] + ln_b[t];
    }
    __syncthreads();

    // proj: 512 outputs x 2-way k-split (k=64)
    {
        int o = t & 511, h = t >> 9;
        float a = 0.0f;
        #pragma unroll
        for (int j = 0; j < 32; ++j) {
            int k = h * 32 + j;
            a = fmaf(xn[k], pw[k * 512 + o], a);
        }
        red[t] = a;
    }
    __syncthreads();
    if (t < 512) lat[t] = red[t] + red[t + 512] + pb[t];
    __syncthreads();

    // fc1: 256 outputs x 4-way k-split (k=512)
    {
        int o = t & 255, h = t >> 8;
        float a = 0.0f;
        #pragma unroll 8
        for (int j = 0; j < 128; ++j) {
            int k = h * 128 + j;
            a = fmaf(lat[k], w1[k * 256 + o], a);
        }
        red[t] = a;
    }
    __syncthreads();
    if (t < 256)
        h1s[t] = fmaxf(red[t] + red[t + 256] + red[t + 512] + red[t + 768] + b1[t], 0.0f);
    __syncthreads();

    // fc2: 512 outputs x 2-way k-split (k=256)
    {
        int o = t & 511, h = t >> 9;
        float a = 0.0f;
        #pragma unroll 8
        for (int j = 0; j < 128; ++j) {
            int k = h * 128 + j;
            a = fmaf(h1s[k], w2[k * 512 + o], a);
        }
        red[t] = a;
    }
    __syncthreads();
    if (t < 512)
        h2out[b * 512 + t] = fmaxf(red[t] + red[t + 512] + b2[t], 0.0f);
}

// ---- final GEMM: out[128,6144] = h2[128,512] @ w3[512,6144] + b3 ----
#define RS 136
__global__ __launch_bounds__(512) void k_final(const float* __restrict__ h2,
                                               const float* __restrict__ w3,
                                               const float* __restrict__ b3,
                                               float* __restrict__ out) {
    __shared__ float h2s[64 * RS];   // 34.8 KB
    const int t = threadIdx.x;
    const int tx = t & 15;
    const int ty = t >> 4;           // 0..31
    const int c = blockIdx.x * 64 + tx * 4;
    const int rbase = blockIdx.y * 64;
    const int r0 = ty * 2;           // local row pair

    float4 bias = *(const float4*)&b3[c];
    float4 acc0 = bias, acc1 = bias;

    const float4* h2g = (const float4*)h2;
    for (int kc = 0; kc < 512; kc += 128) {
        __syncthreads();
        #pragma unroll
        for (int it = 0; it < 4; ++it) {
            int idx = it * 512 + t;
            int rr = idx >> 5;        // 0..63 local row
            int kq = idx & 31;        // 32 float4 per row-chunk
            float4 v = h2g[(rbase + rr) * 128 + (kc >> 2) + kq];
            *(float4*)&h2s[rr * RS + kq * 4] = v;
        }
        __syncthreads();
        for (int k = 0; k < 128; k += 4) {
            float4 A0 = *(const float4*)&h2s[(r0 + 0) * RS + k];
            float4 A1 = *(const float4*)&h2s[(r0 + 1) * RS + k];
            #pragma unroll
            for (int kk = 0; kk < 4; ++kk) {
                float4 w = *(const float4*)&w3[(size_t)(kc + k + kk) * 6144 + c];
                float a0 = (kk == 0) ? A0.x : (kk == 1) ? A0.y : (kk == 2) ? A0.z : A0.w;
                float a1 = (kk == 0) ? A1.x : (kk == 1) ? A1.y : (kk == 2) ? A1.z : A1.w;
                acc0.x = fmaf(a0, w.x, acc0.x); acc0.y = fmaf(a0, w.y, acc0.y);
                acc0.z = fmaf(a0, w.z, acc0.z); acc0.w = fmaf(a0, w.w, acc0.w);
                acc1.x = fmaf(a1, w.x, acc1.x); acc1.y = fmaf(a1, w.y, acc1.y);
                acc1.z = fmaf(a1, w.z, acc1.z); acc1.w = fmaf(a1, w.w, acc1.w);
            }
        }
    }
    *(float4*)&out[(size_t)(rbase + r0 + 0) * 6144 + c] = acc0;
    *(float4*)&out[(size_t)(rbase + r0 + 1) * 6144 + c] = acc1;
}

extern "C" void kernel_launch(void* const* d_in, const int* in_sizes, int n_in,
                              void* d_out, int out_size, void* d_ws, size_t ws_size,
                              hipStream_t stream) {
    const float* feat  = (const float*)d_in[0];
    const int*   batch = (const int*)d_in[1];
    const float* ln_g  = (const float*)d_in[2];
    const float* ln_b  = (const float*)d_in[3];
    const float* pw    = (const float*)d_in[4];
    const float* pb    = (const float*)d_in[5];
    const float* w1    = (const float*)d_in[6];
    const float* b1    = (const float*)d_in[7];
    const float* w2    = (const float*)d_in[8];
    const float* b2    = (const float*)d_in[9];
    const float* w3    = (const float*)d_in[10];
    const float* b3    = (const float*)d_in[11];
    float* out = (float*)d_out;

    unsigned* pool = (unsigned*)d_ws;            // 128*64 uints
    float* h2buf = (float*)d_ws + BSEG * FEAT;   // 128*512 floats

    // enc(-inf) == 0 under the biased encoding -> memset node, no init kernel
    hipMemsetAsync(pool, 0, BSEG * FEAT * sizeof(unsigned), stream);
    k_segmax<<<NBLK_SEG, 256, 0, stream>>>((const float4*)feat, batch, pool);
    k_mlp<<<BSEG, 1024, 0, stream>>>(pool, ln_g, ln_b, pw, pb, w1, b1, w2, b2, h2buf);
    k_final<<<dim3(96, 2), 512, 0, stream>>>(h2buf, w3, b3, out);
}